// Round 14
// baseline (328.460 us; speedup 1.0000x reference)
//
#include <hip/hip_runtime.h>

#define N_NODES  100000
#define N_EDGES  1600000
#define N_GRAPHS 512
#define HID      128
#define NB       782        // fine buckets of 128 nodes (dst >> 7)
#define NCHUNK   782        // edge chunks of 2048 (3 blocks/CU for hist+scatter)
#define CHUNK    2048

typedef unsigned int  uint;
typedef unsigned char uchar;
typedef unsigned short ushort;
typedef __attribute__((ext_vector_type(8))) short  short8;   // 8 bf16 (4 VGPRs)
typedef __attribute__((ext_vector_type(4))) float  f32x4;
typedef __attribute__((ext_vector_type(2))) float  f32x2;

__device__ inline float bflo(uint u) { return __uint_as_float(u << 16); }
__device__ inline float bfhi(uint u) { return __uint_as_float(u & 0xffff0000u); }
__device__ inline ushort f2bf(float f) {
    uint u = __float_as_uint(f);
    return (ushort)((u + 0x7fffu + ((u >> 16) & 1u)) >> 16);   // RNE
}
__device__ inline uint pk(float a, float b) {
    return (uint)f2bf(a) | ((uint)f2bf(b) << 16);
}

// unmasked 16-fp8 accumulate into f32x2 pairs (v_pk_add_f32 eligible)
__device__ inline void acc16_pk(uint4 hv, f32x2* a) {
    a[0] += __builtin_amdgcn_cvt_pk_f32_fp8((int)hv.x, false);
    a[1] += __builtin_amdgcn_cvt_pk_f32_fp8((int)hv.x, true);
    a[2] += __builtin_amdgcn_cvt_pk_f32_fp8((int)hv.y, false);
    a[3] += __builtin_amdgcn_cvt_pk_f32_fp8((int)hv.y, true);
    a[4] += __builtin_amdgcn_cvt_pk_f32_fp8((int)hv.z, false);
    a[5] += __builtin_amdgcn_cvt_pk_f32_fp8((int)hv.z, true);
    a[6] += __builtin_amdgcn_cvt_pk_f32_fp8((int)hv.w, false);
    a[7] += __builtin_amdgcn_cvt_pk_f32_fp8((int)hv.w, true);
}
// masked variant (tail batch only); w in {0,1} so w* is exact
__device__ inline void acc16_w(uint4 hv, float w, f32x2* a) {
    a[0] += w * __builtin_amdgcn_cvt_pk_f32_fp8((int)hv.x, false);
    a[1] += w * __builtin_amdgcn_cvt_pk_f32_fp8((int)hv.x, true);
    a[2] += w * __builtin_amdgcn_cvt_pk_f32_fp8((int)hv.y, false);
    a[3] += w * __builtin_amdgcn_cvt_pk_f32_fp8((int)hv.y, true);
    a[4] += w * __builtin_amdgcn_cvt_pk_f32_fp8((int)hv.z, false);
    a[5] += w * __builtin_amdgcn_cvt_pk_f32_fp8((int)hv.z, true);
    a[6] += w * __builtin_amdgcn_cvt_pk_f32_fp8((int)hv.w, false);
    a[7] += w * __builtin_amdgcn_cvt_pk_f32_fp8((int)hv.w, true);
}

// ---------------- prep: pack W | boundaries | cvt temb | coarse hist | zero pooled ----
// blocks: [0,224) pack, [224,615) boundary, [615,3740) temb, [3740,4522) hist,
//         [4522,4778) pooled zero
__global__ __launch_bounds__(256)
void prep_kernel(const float* __restrict__ Wt, const float* __restrict__ W1,
                 const float* __restrict__ Ws, ushort* __restrict__ packed,
                 const int* __restrict__ batch, int* __restrict__ gstart,
                 const float* __restrict__ temb, ushort* __restrict__ tembb,
                 const int* __restrict__ dst, int* __restrict__ chunk_hist,
                 float* __restrict__ pooled) {
    __shared__ int h[NB];
    int b = blockIdx.x;
    int t = threadIdx.x;
    if (b < 224) {                          // pack weights into MFMA B-frag order
        int tid = b * 256 + t;
        const float* src; int p; ushort* dstp;
        if (tid < 16384)      { src = Wt;         p = tid;         dstp = packed; }
        else if (tid < 24576) { src = W1;         p = tid - 16384; dstp = packed + 16384; }
        else if (tid < 40960) { src = Ws;         p = tid - 24576; dstp = packed + 24576; }
        else                  { src = Ws + 16384; p = tid - 40960; dstp = packed + 40960; }
        int j  = p & 7;
        int L  = (p >> 3) & 63;
        int cb = (p >> 9) & 7;
        int s  = p >> 12;
        int k  = s * 32 + (L >> 4) * 8 + j;
        int n  = cb * 16 + (L & 15);
        dstp[p] = f2bf(src[k * 128 + n]);
    } else if (b < 615) {                   // graph boundary scan (batch sorted)
        int i = (b - 224) * 256 + t;
        if (i >= N_NODES) return;
        int bb = batch[i];
        int prev = (i == 0) ? -1 : batch[i - 1];
        for (int g = prev + 1; g <= bb; ++g) gstart[g] = i;
        if (i == N_NODES - 1) {
            for (int g = bb + 1; g <= N_GRAPHS; ++g) gstart[g] = N_NODES;
        }
    } else if (b < 3740) {                  // cvt temb (N*128 floats, 16/thread, exact)
        long i = ((long)(b - 615) * 256 + t) * 16;
#pragma unroll
        for (int k = 0; k < 4; ++k) {
            float4 f = *(const float4*)(temb + i + k * 4);
            uint2 o; o.x = pk(f.x, f.y); o.y = pk(f.z, f.w);
            *(uint2*)(tembb + i + k * 4) = o;
        }
    } else if (b < 4522) {                  // coarse histogram per 2048-edge chunk
        int c = b - 3740;
        for (int i = t; i < NB; i += 256) h[i] = 0;
        __syncthreads();
        const int4* d4 = (const int4*)dst;
#pragma unroll
        for (int k = 0; k < 2; ++k) {
            int i4 = c * (CHUNK / 4) + k * 256 + t;
            if (i4 < N_EDGES / 4) {
                int4 d = d4[i4];
                atomicAdd(&h[d.x >> 7], 1);
                atomicAdd(&h[d.y >> 7], 1);
                atomicAdd(&h[d.z >> 7], 1);
                atomicAdd(&h[d.w >> 7], 1);
            }
        }
        __syncthreads();
        for (int i = t; i < NB; i += 256) chunk_hist[c * NB + i] = h[i];
    } else {                                // zero pooled accumulators (512*128)
        pooled[(b - 4522) * 256 + t] = 0.f;
    }
}

// ---------------- CSR build v3: parallel bucketed counting sort ----------------

// scanA: one block per bucket — ordered prefix over 782 chunks (4 vals/thread)
__global__ __launch_bounds__(256)
void scanA(const int* __restrict__ chunk_hist, int* __restrict__ cbaseT,
           int* __restrict__ btotal) {
    __shared__ int sc[256];
    int b = blockIdx.x, t = threadIdx.x;
    int v[4]; int sum = 0;
#pragma unroll
    for (int k = 0; k < 4; ++k) {
        int c = t * 4 + k;
        v[k] = (c < NCHUNK) ? chunk_hist[c * NB + b] : 0;
        sum += v[k];
    }
    sc[t] = sum;
    __syncthreads();
    for (int off = 1; off < 256; off <<= 1) {
        int x = (t >= off) ? sc[t - off] : 0;
        __syncthreads();
        sc[t] += x;
        __syncthreads();
    }
    int run = sc[t] - sum;
#pragma unroll
    for (int k = 0; k < 4; ++k) {
        int c = t * 4 + k;
        if (c < NCHUNK) cbaseT[b * NCHUNK + c] = run;
        run += v[k];
    }
    if (t == 255) btotal[b] = sc[255];
}

// scanB: single tiny block — exclusive scan of 782 bucket totals
__global__ __launch_bounds__(256)
void scanB(const int* __restrict__ btotal, int* __restrict__ bstart,
           int* __restrict__ row_ptr) {
    __shared__ int sc[256];
    int t = threadIdx.x;
    int v[4]; int sum = 0;
#pragma unroll
    for (int k = 0; k < 4; ++k) {
        int idx = t * 4 + k;
        v[k] = (idx < NB) ? btotal[idx] : 0;
        sum += v[k];
    }
    sc[t] = sum;
    __syncthreads();
    for (int off = 1; off < 256; off <<= 1) {
        int x = (t >= off) ? sc[t - off] : 0;
        __syncthreads();
        sc[t] += x;
        __syncthreads();
    }
    int run = sc[t] - sum;
#pragma unroll
    for (int k = 0; k < 4; ++k) {
        int idx = t * 4 + k;
        if (idx < NB) bstart[idx] = run;
        run += v[k];
    }
    if (t == 0) { bstart[NB] = N_EDGES; row_ptr[N_NODES] = N_EDGES; }
}

// scatter: per-chunk into tmp — contiguous runs per bucket (bases = cbaseT + bstart)
__global__ __launch_bounds__(256)
void scatter_coarse(const int* __restrict__ src, const int* __restrict__ dst,
                    const int* __restrict__ cbaseT, const int* __restrict__ bstart,
                    uint* __restrict__ tmp) {
    __shared__ int cur[NB];
    int c = blockIdx.x, t = threadIdx.x;
    for (int i = t; i < NB; i += 256) cur[i] = cbaseT[i * NCHUNK + c] + bstart[i];
    __syncthreads();
    const int4* s4p = (const int4*)src;
    const int4* d4p = (const int4*)dst;
#pragma unroll
    for (int k = 0; k < 2; ++k) {
        int i4 = c * (CHUNK / 4) + k * 256 + t;
        if (i4 < N_EDGES / 4) {
            int4 s = s4p[i4];
            int4 d = d4p[i4];
            int p;
            p = atomicAdd(&cur[d.x >> 7], 1); tmp[p] = (uint)s.x | (((uint)(d.x & 127)) << 17);
            p = atomicAdd(&cur[d.y >> 7], 1); tmp[p] = (uint)s.y | (((uint)(d.y & 127)) << 17);
            p = atomicAdd(&cur[d.z >> 7], 1); tmp[p] = (uint)s.z | (((uint)(d.z & 127)) << 17);
            p = atomicAdd(&cur[d.w >> 7], 1); tmp[p] = (uint)s.w | (((uint)(d.w & 127)) << 17);
        }
    }
}

// csr_fine: one block per 128-node bucket — local hist+scan -> row_ptr/dinv,
// fine scatter, fused xb8 = fp8(dinv * x)
__global__ __launch_bounds__(256)
void csr_fine(const uint* __restrict__ tmp, const int* __restrict__ bstart,
              int* __restrict__ row_ptr, float* __restrict__ dinv,
              int* __restrict__ edge, const float* __restrict__ x,
              uchar* __restrict__ xb8) {
    __shared__ int   cnt[128];
    __shared__ float dvloc[128];
    __shared__ int   ps[128];
    int b = blockIdx.x, t = threadIdx.x;
    int node0 = b << 7;
    int ncnt = min(128, N_NODES - node0);
    int s = bstart[b], e = bstart[b + 1];
    if (t < 128) cnt[t] = 0;
    __syncthreads();
    for (int i = s + t; i < e; i += 256) atomicAdd(&cnt[tmp[i] >> 17], 1);
    __syncthreads();
    int c0 = (t < 128) ? cnt[t] : 0;
    if (t < 128) ps[t] = c0;
    __syncthreads();
    for (int off = 1; off < 128; off <<= 1) {
        int v = (t < 128 && t >= off) ? ps[t - off] : 0;
        __syncthreads();
        if (t < 128) ps[t] += v;
        __syncthreads();
    }
    if (t < 128) {
        int p0 = s + ps[t] - c0;
        float dv = rsqrtf((float)(c0 + 1));
        if (t < ncnt) { row_ptr[node0 + t] = p0; dinv[node0 + t] = dv; }
        dvloc[t] = dv;
        cnt[t] = p0;                         // counts -> absolute cursors
    }
    __syncthreads();
    for (int i = s + t; i < e; i += 256) {
        uint rec = tmp[i];
        int p = atomicAdd(&cnt[rec >> 17], 1);
        edge[p] = (int)(rec & 0x1FFFFu);
    }
    // fused: xb8 rows for this bucket = fp8(dinv * x)  (4 feats -> 1 uint per idx)
    for (int idx = t; idx < ncnt * 16; idx += 256) {
        int row = idx >> 4, q = idx & 15;
        float4 f = ((const float4*)(x + (size_t)(node0 + row) * 64))[q];
        float d = dvloc[row];
        int w = __builtin_amdgcn_cvt_pk_fp8_f32(f.x * d, f.y * d, 0, false);
        w     = __builtin_amdgcn_cvt_pk_fp8_f32(f.z * d, f.w * d, w, true);
        *(uint*)(xb8 + (size_t)(node0 + row) * 64 + q * 4) = (uint)w;
    }
}

// ---------------- fused GCN conv ----------------
// input rows are G = dinv*H (fp8); agg_v = dinv_v * (sum_{s in N(v)} G_s + G_v)
// O = relu(agg @ W + b) [+ relu(tembb @ Wt + bt)]; SCALEOUT: store dinv*O
// R14: TILE is a template param. K=128 convs use TILE=8 (one row per 8-lane group,
// RPG=1, no pairing) -> 12500 waves of work vs 6250: raises resident waves/CU from
// the grid-imposed 24 toward the 28 allowed by VGPR(73)/LDS(12.8KB) — the one axis
// all prior conv variants held fixed. MFMA M=16 half-waste is free (Mfma ~3%);
// C row i depends only on A row i (R2-proven), garbage rows never stored.
template <int K, int TILE, int MW, bool TEMB, bool OUT8, bool SCALEOUT, bool POOL>
__global__ __launch_bounds__(256, MW)
void fused_conv(const void* __restrict__ Hv, const int* __restrict__ rp,
                const int* __restrict__ edge, const float* __restrict__ dinv,
                const ushort* __restrict__ Wp, const float* __restrict__ bias,
                const ushort* __restrict__ tembb, const ushort* __restrict__ Wtp,
                const float* __restrict__ bias_t, void* __restrict__ Ov,
                const int* __restrict__ batchp, float* __restrict__ pooled, int ntiles) {
    constexpr int LPR  = K / 16;      // lanes per row (16 fp8 feats/lane)
    constexpr int G    = 64 / LPR;    // concurrent rows per wave (8 or 16)
    static_assert(G >= TILE, "one row per group");
    constexpr int U    = 8;           // edge-walk unroll depth
    constexpr int LROW = 136;         // LDS row stride in shorts (bf16 staging)
    constexpr int ECAP = (TILE == 16) ? 512 : 256;  // span cap: mean 16*TILE+1 deg
    __shared__ __align__(16) ushort sA[4][16 * LROW];
    __shared__ uint sE[4][ECAP];      // per-wave edge-span stage
    const int wave = threadIdx.x >> 6;
    const int lane = threadIdx.x & 63;
    const int tile = blockIdx.x * 4 + wave;
    if (tile >= ntiles) return;       // per-wave LDS, no barriers: safe
    const int row0 = tile * TILE;
    const int g  = lane / LPR;
    const int fq = lane % LPR;
    ushort* myA = sA[wave];
    const uchar* H8 = (const uchar*)Hv;

    // lane-parallel preload of row_ptr[TILE+1] / dinv[TILE]; broadcast via shfl
    int   rpv = rp[row0 + ((lane <= TILE) ? lane : TILE)];
    float dvv = dinv[row0 + ((lane < TILE) ? lane : TILE - 1)];

    // ---- stage the tile's contiguous edge span into LDS (coalesced) ----
    const int s0   = __shfl(rpv, 0);
    const int eT   = __shfl(rpv, TILE);
    const int ecnt = eT - s0;
    uint* sEw = sE[wave];
    for (int i = lane; i < ecnt && i < ECAP; i += 64)
        sEw[i] = ((const uint*)edge)[s0 + i];

    // ---- phase 1: each group gathers its own row (16B/lane, no reduce) ----
    auto phase1 = [&](auto eload) {
        int r = (g < TILE) ? g : TILE - 1;    // G==TILE always here; defensive
        int v = row0 + r;
        int s = __shfl(rpv, r), e = __shfl(rpv, r + 1);
        f32x2 a[8];
        // self-loop init: a = G_v
        {
            uint4 xv = *(const uint4*)(H8 + (size_t)v * K + fq * 16);
            a[0] = __builtin_amdgcn_cvt_pk_f32_fp8((int)xv.x, false);
            a[1] = __builtin_amdgcn_cvt_pk_f32_fp8((int)xv.x, true);
            a[2] = __builtin_amdgcn_cvt_pk_f32_fp8((int)xv.y, false);
            a[3] = __builtin_amdgcn_cvt_pk_f32_fp8((int)xv.y, true);
            a[4] = __builtin_amdgcn_cvt_pk_f32_fp8((int)xv.z, false);
            a[5] = __builtin_amdgcn_cvt_pk_f32_fp8((int)xv.z, true);
            a[6] = __builtin_amdgcn_cvt_pk_f32_fp8((int)xv.w, false);
            a[7] = __builtin_amdgcn_cvt_pk_f32_fp8((int)xv.w, true);
        }
        int nfull = (e - s) / U;          // group-uniform
        int j = s;
        for (int i = 0; i < nfull; ++i, j += U) {   // full batches: no masks
            int sv[U];
#pragma unroll
            for (int u = 0; u < U; ++u) sv[u] = eload(j + u);
            uint4 hv[U];
#pragma unroll
            for (int u = 0; u < U; ++u)
                hv[u] = *(const uint4*)(H8 + (size_t)sv[u] * K + fq * 16);
#pragma unroll
            for (int u = 0; u < U; ++u) acc16_pk(hv[u], a);
        }
        if (j < e) {                       // one masked tail batch
            int sv[U];
#pragma unroll
            for (int u = 0; u < U; ++u) {
                int jv = j + u;
                int jj = (jv < e) ? jv : e - 1;   // j<e => e>s => e-1 valid
                sv[u] = eload(jj);
            }
            uint4 hv[U];
#pragma unroll
            for (int u = 0; u < U; ++u)
                hv[u] = *(const uint4*)(H8 + (size_t)sv[u] * K + fq * 16);
#pragma unroll
            for (int u = 0; u < U; ++u) {
                float w = (j + u < e) ? 1.0f : 0.0f;
                acc16_w(hv[u], w, a);
            }
        }
        float dv = __shfl(dvv, r);        // row-uniform scale
        uint4 o1, o2;
        o1.x = pk(a[0].x * dv, a[0].y * dv); o1.y = pk(a[1].x * dv, a[1].y * dv);
        o1.z = pk(a[2].x * dv, a[2].y * dv); o1.w = pk(a[3].x * dv, a[3].y * dv);
        o2.x = pk(a[4].x * dv, a[4].y * dv); o2.y = pk(a[5].x * dv, a[5].y * dv);
        o2.z = pk(a[6].x * dv, a[6].y * dv); o2.w = pk(a[7].x * dv, a[7].y * dv);
        *(uint4*)(myA + r * LROW + fq * 16)     = o1;
        *(uint4*)(myA + r * LROW + fq * 16 + 8) = o2;
    };
    if (ecnt <= ECAP) {
        phase1([&](int jj) { return (int)sEw[jj - s0]; });       // LDS path (normal)
    } else {
        phase1([&](int jj) { return (int)((const uint*)edge)[jj]; });  // fallback
    }

    // ---- phase 2: MFMA (A from LDS, B packed from global/L2) ----
    // rows TILE..15 of myA are stale; C row i depends only on A row i -> safe.
    const int m = lane & 15, q = lane >> 4;
    f32x4 acc[8];
#pragma unroll
    for (int cb = 0; cb < 8; ++cb) acc[cb] = {0.f, 0.f, 0.f, 0.f};
    constexpr int S = K / 32;
#pragma unroll
    for (int s = 0; s < S; ++s) {
        short8 av = *(const short8*)(myA + m * LROW + s * 32 + q * 8);
#pragma unroll
        for (int cb = 0; cb < 8; ++cb) {
            short8 b = *(const short8*)(Wp + (size_t)((s * 8 + cb) * 64 + lane) * 8);
            acc[cb] = __builtin_amdgcn_mfma_f32_16x16x32_bf16(av, b, acc[cb], 0, 0, 0);
        }
    }

    // ---- phase 2b (TEMB): second MFMA chain, A = prepacked bf16 temb rows ----
    f32x4 acc2[TEMB ? 8 : 1];
    if constexpr (TEMB) {
#pragma unroll
        for (int cb = 0; cb < 8; ++cb) acc2[cb] = {0.f, 0.f, 0.f, 0.f};
        const ushort* Arow = tembb + (size_t)(row0 + m) * 128 + q * 8;
#pragma unroll
        for (int s2 = 0; s2 < 4; ++s2) {
            short8 av = *(const short8*)(Arow + s2 * 32);
#pragma unroll
            for (int cb = 0; cb < 8; ++cb) {
                short8 b = *(const short8*)(Wtp + (size_t)((s2 * 8 + cb) * 64 + lane) * 8);
                acc2[cb] = __builtin_amdgcn_mfma_f32_16x16x32_bf16(av, b, acc2[cb], 0, 0, 0);
            }
        }
    }

    // ---- phase 3: epilogue into LDS staging, then store / pool (TILE rows) ----
    // C/D layout: col = lane&15, row = (lane>>4)*4 + r
    float dsc[4];
    if constexpr (SCALEOUT) {
#pragma unroll
        for (int r = 0; r < 4; ++r) {
            int rr = q * 4 + r;
            dsc[r] = __shfl(dvv, (rr < TILE) ? rr : TILE - 1);
        }
    }
    if constexpr (!OUT8) {
        ushort* Ob = (ushort*)Ov;
#pragma unroll
        for (int cb = 0; cb < 8; ++cb) {
            int colc = cb * 16 + m;
            float bv = bias[colc];
            float bt2 = TEMB ? bias_t[colc] : 0.f;
#pragma unroll
            for (int r = 0; r < 4; ++r) {
                int row = q * 4 + r;
                float v = fmaxf(acc[cb][r] + bv, 0.0f);
                if (TEMB) v += fmaxf(acc2[cb][r] + bt2, 0.0f);
                if (SCALEOUT) v *= dsc[r];
                myA[row * LROW + colc] = f2bf(v);
            }
        }
        if constexpr (!POOL) {
#pragma unroll
            for (int i = 0; i < TILE / 4; ++i) {
                int srow = i * 4 + (lane >> 4);
                int scol = (lane & 15) * 8;
                *(short8*)(Ob + (size_t)(row0 + srow) * 128 + scol) =
                    *(const short8*)(myA + srow * LROW + scol);
            }
        } else {
            // per-graph segment sums over TILE rows (batch sorted), 2 cols/lane
            int gidv = (lane < TILE) ? batchp[row0 + lane] : 0;
            int colb = lane * 2;
            float p0 = 0.f, p1 = 0.f;
#pragma unroll
            for (int r = 0; r < TILE; ++r) {
                uint u = *(const uint*)(myA + r * LROW + colb);
                p0 += bflo(u); p1 += bfhi(u);
                int curg  = __shfl(gidv, r);
                int nextg = (r < TILE - 1) ? __shfl(gidv, r + 1) : -1;
                if (nextg != curg) {
                    atomicAdd(&pooled[curg * 128 + colb],     p0);
                    atomicAdd(&pooled[curg * 128 + colb + 1], p1);
                    p0 = 0.f; p1 = 0.f;
                }
            }
        }
    } else {
        uchar* st8 = (uchar*)myA;           // byte staging, row stride 136 B
        uchar* Ob = (uchar*)Ov;
#pragma unroll
        for (int cb = 0; cb < 8; ++cb) {
            int colc = cb * 16 + m;
            float bv = bias[colc];
            float bt2 = TEMB ? bias_t[colc] : 0.f;
#pragma unroll
            for (int r = 0; r < 4; ++r) {
                int row = q * 4 + r;
                float v = fmaxf(acc[cb][r] + bv, 0.0f);
                if (TEMB) v += fmaxf(acc2[cb][r] + bt2, 0.0f);
                if (SCALEOUT) v *= dsc[r];
                int enc = __builtin_amdgcn_cvt_pk_fp8_f32(v, v, 0, false);
                st8[row * 136 + colc] = (uchar)(enc & 0xff);
            }
        }
        // TILE rows * 128 B; 64 lanes * 8 B = 512 B/iter -> TILE/4 iters
#pragma unroll
        for (int i = 0; i < TILE / 4; ++i) {
            int idx = i * 64 + lane;        // [0, TILE*16)
            int srow = idx >> 4;            // [0, TILE)
            int soff = (idx & 15) * 8;      // [0,128) step 8
            *(uint2*)(Ob + (size_t)(row0 + srow) * 128 + soff) =
                *(const uint2*)(st8 + srow * 136 + soff);
        }
    }
}

// ---------------- output head: out[g] = (pooled[g]/cnt) @ Wo + bo ----------------

__global__ __launch_bounds__(256)
void head_kernel(const float* __restrict__ pooled, const int* __restrict__ gstart,
                 const float* __restrict__ Wo, const float* __restrict__ bo,
                 float* __restrict__ out) {
    int g  = blockIdx.x * 16 + (threadIdx.x >> 4);
    int tg = threadIdx.x & 15;
    if (g >= N_GRAPHS) return;
    int c = gstart[g + 1] - gstart[g];
    float inv = 1.0f / (float)(c < 1 ? 1 : c);
    float acc = bo[tg];
    for (int k = 0; k < HID; ++k)
        acc += pooled[g * 128 + k] * inv * Wo[k * 16 + tg];
    out[g * 16 + tg] = acc;
}

// ---------------- launch ----------------

extern "C" void kernel_launch(void* const* d_in, const int* in_sizes, int n_in,
                              void* d_out, int out_size, void* d_ws, size_t ws_size,
                              hipStream_t stream) {
    const float* x       = (const float*)d_in[0];
    const int*   ei      = (const int*)d_in[1];
    const float* temb_in = (const float*)d_in[2];
    const int*   batch   = (const int*)d_in[3];
    const float* Wt      = (const float*)d_in[4];
    const float* bt      = (const float*)d_in[5];
    const float* W1      = (const float*)d_in[6];
    const float* b1      = (const float*)d_in[7];
    const float* Ws      = (const float*)d_in[8];
    const float* bs      = (const float*)d_in[9];
    const float* Wo      = (const float*)d_in[10];
    const float* bo      = (const float*)d_in[11];
    float* out = (float*)d_out;

    const int N = N_NODES, E = N_EDGES;
    const int* src = ei;
    const int* dst = ei + E;

    char* p = (char*)d_ws;
    auto carve = [&](size_t bytes) -> void* {
        void* r = (void*)p;
        p += (bytes + 255) & ~(size_t)255;
        return r;
    };
    int*    row_ptr    = (int*)carve((size_t)(N + 1) * 4);
    float*  dinv       = (float*)carve((size_t)N * 4);
    int*    gstart     = (int*)carve((size_t)(N_GRAPHS + 1) * 4);
    ushort* packed     = (ushort*)carve((size_t)57344 * 2);
    int*    chunk_hist = (int*)carve((size_t)NCHUNK * NB * 4);
    int*    cbaseT     = (int*)carve((size_t)NB * NCHUNK * 4);
    int*    btotal     = (int*)carve((size_t)NB * 4);
    int*    bstart     = (int*)carve((size_t)(NB + 1) * 4);
    uint*   tmp        = (uint*)carve((size_t)E * 4);
    int*    edge       = (int*)carve((size_t)E * 4);
    uchar*  xb8        = (uchar*)carve((size_t)(N + 16) * 64);
    ushort* tembb      = (ushort*)carve((size_t)N * 128 * 2);
    uchar*  H1f8       = (uchar*)carve((size_t)(N + 16) * 128);
    uchar*  H2f8       = (uchar*)carve((size_t)(N + 16) * 128);
    float*  pooled     = (float*)carve((size_t)N_GRAPHS * 128 * 4);

    const ushort* Wtp  = packed;
    const ushort* W1p  = packed + 16384;
    const ushort* Ws0p = packed + 24576;
    const ushort* Ws1p = packed + 40960;

    const int nt16  = N / 16;             // 6250  (conv1: 16-row tiles)
    const int gblk1 = (nt16 + 3) / 4;     // 1563
    const int nt8   = N / 8;              // 12500 (conv2/3: 8-row tiles)
    const int gblk2 = (nt8 + 3) / 4;      // 3125

    // prep: pack W | boundaries | cvt temb | coarse hist | zero pooled
    prep_kernel<<<4778, 256, 0, stream>>>(Wt, W1, Ws, packed, batch, gstart,
                                          temb_in, tembb, dst, chunk_hist, pooled);

    // CSR build v3 (parallel scans; 782 buckets x 782 chunks)
    scanA<<<NB, 256, 0, stream>>>(chunk_hist, cbaseT, btotal);
    scanB<<<1, 256, 0, stream>>>(btotal, bstart, row_ptr);
    scatter_coarse<<<NCHUNK, 256, 0, stream>>>(src, dst, cbaseT, bstart, tmp);
    csr_fine<<<NB, 256, 0, stream>>>(tmp, bstart, row_ptr, dinv, edge, x, xb8);

    // conv1 (+fused temb layer): H1f8 = dinv * (relu(agg(G0)@W1+b1) + relu(tembb@Wt+bt))
    fused_conv<64, 16, 6, true, true, true, false><<<gblk1, 256, 0, stream>>>(
        xb8, row_ptr, edge, dinv, W1p, b1, tembb, Wtp, bt, H1f8,
        nullptr, nullptr, nt16);
    // conv2 (fp8 gather, fp8 out, 8-row tiles): H2f8 = dinv * relu(agg(H1f8)@Ws0 + bs0)
    fused_conv<128, 8, 7, false, true, true, false><<<gblk2, 256, 0, stream>>>(
        H1f8, row_ptr, edge, dinv, Ws0p, bs, nullptr, nullptr, nullptr, H2f8,
        nullptr, nullptr, nt8);
    // conv3 (fp8 gather, fused pooling, 8-row tiles)
    fused_conv<128, 8, 7, false, false, false, true><<<gblk2, 256, 0, stream>>>(
        H2f8, row_ptr, edge, dinv, Ws1p, bs + 128, nullptr, nullptr, nullptr, nullptr,
        batch, pooled, nt8);

    // head: out = (pooled/cnt) @ Wo + bo
    head_kernel<<<32, 256, 0, stream>>>(pooled, gstart, Wo, bo, out);
}

// Round 15
// 303.947 us; speedup vs baseline: 1.0806x; 1.0806x over previous
//
#include <hip/hip_runtime.h>

#define N_NODES  100000
#define N_EDGES  1600000
#define N_GRAPHS 512
#define HID      128
#define NB       782        // fine buckets of 128 nodes (dst >> 7)
#define NCHUNK   782        // edge chunks of 2048 (3 blocks/CU for hist+scatter)
#define CHUNK    2048

typedef unsigned int  uint;
typedef unsigned char uchar;
typedef unsigned short ushort;
typedef __attribute__((ext_vector_type(8))) short  short8;   // 8 bf16 (4 VGPRs)
typedef __attribute__((ext_vector_type(4))) float  f32x4;
typedef __attribute__((ext_vector_type(2))) float  f32x2;

__device__ inline float bflo(uint u) { return __uint_as_float(u << 16); }
__device__ inline float bfhi(uint u) { return __uint_as_float(u & 0xffff0000u); }
__device__ inline ushort f2bf(float f) {
    uint u = __float_as_uint(f);
    return (ushort)((u + 0x7fffu + ((u >> 16) & 1u)) >> 16);   // RNE
}
__device__ inline uint pk(float a, float b) {
    return (uint)f2bf(a) | ((uint)f2bf(b) << 16);
}

// unmasked 16-fp8 accumulate into f32x2 pairs (v_pk_add_f32 eligible)
__device__ inline void acc16_pk(uint4 hv, f32x2* a) {
    a[0] += __builtin_amdgcn_cvt_pk_f32_fp8((int)hv.x, false);
    a[1] += __builtin_amdgcn_cvt_pk_f32_fp8((int)hv.x, true);
    a[2] += __builtin_amdgcn_cvt_pk_f32_fp8((int)hv.y, false);
    a[3] += __builtin_amdgcn_cvt_pk_f32_fp8((int)hv.y, true);
    a[4] += __builtin_amdgcn_cvt_pk_f32_fp8((int)hv.z, false);
    a[5] += __builtin_amdgcn_cvt_pk_f32_fp8((int)hv.z, true);
    a[6] += __builtin_amdgcn_cvt_pk_f32_fp8((int)hv.w, false);
    a[7] += __builtin_amdgcn_cvt_pk_f32_fp8((int)hv.w, true);
}
// masked variant (tail batch only); w in {0,1} so w* is exact
__device__ inline void acc16_w(uint4 hv, float w, f32x2* a) {
    a[0] += w * __builtin_amdgcn_cvt_pk_f32_fp8((int)hv.x, false);
    a[1] += w * __builtin_amdgcn_cvt_pk_f32_fp8((int)hv.x, true);
    a[2] += w * __builtin_amdgcn_cvt_pk_f32_fp8((int)hv.y, false);
    a[3] += w * __builtin_amdgcn_cvt_pk_f32_fp8((int)hv.y, true);
    a[4] += w * __builtin_amdgcn_cvt_pk_f32_fp8((int)hv.z, false);
    a[5] += w * __builtin_amdgcn_cvt_pk_f32_fp8((int)hv.z, true);
    a[6] += w * __builtin_amdgcn_cvt_pk_f32_fp8((int)hv.w, false);
    a[7] += w * __builtin_amdgcn_cvt_pk_f32_fp8((int)hv.w, true);
}

// ---------------- prep: pack W | boundaries | cvt temb | coarse hist | zero pooled ----
// blocks: [0,224) pack, [224,615) boundary, [615,3740) temb, [3740,4522) hist,
//         [4522,4778) pooled zero
__global__ __launch_bounds__(256)
void prep_kernel(const float* __restrict__ Wt, const float* __restrict__ W1,
                 const float* __restrict__ Ws, ushort* __restrict__ packed,
                 const int* __restrict__ batch, int* __restrict__ gstart,
                 const float* __restrict__ temb, ushort* __restrict__ tembb,
                 const int* __restrict__ dst, int* __restrict__ chunk_hist,
                 float* __restrict__ pooled) {
    __shared__ int h[NB];
    int b = blockIdx.x;
    int t = threadIdx.x;
    if (b < 224) {                          // pack weights into MFMA B-frag order
        int tid = b * 256 + t;
        const float* src; int p; ushort* dstp;
        if (tid < 16384)      { src = Wt;         p = tid;         dstp = packed; }
        else if (tid < 24576) { src = W1;         p = tid - 16384; dstp = packed + 16384; }
        else if (tid < 40960) { src = Ws;         p = tid - 24576; dstp = packed + 24576; }
        else                  { src = Ws + 16384; p = tid - 40960; dstp = packed + 40960; }
        int j  = p & 7;
        int L  = (p >> 3) & 63;
        int cb = (p >> 9) & 7;
        int s  = p >> 12;
        int k  = s * 32 + (L >> 4) * 8 + j;
        int n  = cb * 16 + (L & 15);
        dstp[p] = f2bf(src[k * 128 + n]);
    } else if (b < 615) {                   // graph boundary scan (batch sorted)
        int i = (b - 224) * 256 + t;
        if (i >= N_NODES) return;
        int bb = batch[i];
        int prev = (i == 0) ? -1 : batch[i - 1];
        for (int g = prev + 1; g <= bb; ++g) gstart[g] = i;
        if (i == N_NODES - 1) {
            for (int g = bb + 1; g <= N_GRAPHS; ++g) gstart[g] = N_NODES;
        }
    } else if (b < 3740) {                  // cvt temb (N*128 floats, 16/thread, exact)
        long i = ((long)(b - 615) * 256 + t) * 16;
#pragma unroll
        for (int k = 0; k < 4; ++k) {
            float4 f = *(const float4*)(temb + i + k * 4);
            uint2 o; o.x = pk(f.x, f.y); o.y = pk(f.z, f.w);
            *(uint2*)(tembb + i + k * 4) = o;
        }
    } else if (b < 4522) {                  // coarse histogram per 2048-edge chunk
        int c = b - 3740;
        for (int i = t; i < NB; i += 256) h[i] = 0;
        __syncthreads();
        const int4* d4 = (const int4*)dst;
#pragma unroll
        for (int k = 0; k < 2; ++k) {
            int i4 = c * (CHUNK / 4) + k * 256 + t;
            if (i4 < N_EDGES / 4) {
                int4 d = d4[i4];
                atomicAdd(&h[d.x >> 7], 1);
                atomicAdd(&h[d.y >> 7], 1);
                atomicAdd(&h[d.z >> 7], 1);
                atomicAdd(&h[d.w >> 7], 1);
            }
        }
        __syncthreads();
        for (int i = t; i < NB; i += 256) chunk_hist[c * NB + i] = h[i];
    } else {                                // zero pooled accumulators (512*128)
        pooled[(b - 4522) * 256 + t] = 0.f;
    }
}

// ---------------- CSR build v3: parallel bucketed counting sort ----------------

// scanA: one block per bucket — ordered prefix over 782 chunks (4 vals/thread)
__global__ __launch_bounds__(256)
void scanA(const int* __restrict__ chunk_hist, int* __restrict__ cbaseT,
           int* __restrict__ btotal) {
    __shared__ int sc[256];
    int b = blockIdx.x, t = threadIdx.x;
    int v[4]; int sum = 0;
#pragma unroll
    for (int k = 0; k < 4; ++k) {
        int c = t * 4 + k;
        v[k] = (c < NCHUNK) ? chunk_hist[c * NB + b] : 0;
        sum += v[k];
    }
    sc[t] = sum;
    __syncthreads();
    for (int off = 1; off < 256; off <<= 1) {
        int x = (t >= off) ? sc[t - off] : 0;
        __syncthreads();
        sc[t] += x;
        __syncthreads();
    }
    int run = sc[t] - sum;
#pragma unroll
    for (int k = 0; k < 4; ++k) {
        int c = t * 4 + k;
        if (c < NCHUNK) cbaseT[b * NCHUNK + c] = run;
        run += v[k];
    }
    if (t == 255) btotal[b] = sc[255];
}

// scanB: single tiny block — exclusive scan of 782 bucket totals
__global__ __launch_bounds__(256)
void scanB(const int* __restrict__ btotal, int* __restrict__ bstart,
           int* __restrict__ row_ptr) {
    __shared__ int sc[256];
    int t = threadIdx.x;
    int v[4]; int sum = 0;
#pragma unroll
    for (int k = 0; k < 4; ++k) {
        int idx = t * 4 + k;
        v[k] = (idx < NB) ? btotal[idx] : 0;
        sum += v[k];
    }
    sc[t] = sum;
    __syncthreads();
    for (int off = 1; off < 256; off <<= 1) {
        int x = (t >= off) ? sc[t - off] : 0;
        __syncthreads();
        sc[t] += x;
        __syncthreads();
    }
    int run = sc[t] - sum;
#pragma unroll
    for (int k = 0; k < 4; ++k) {
        int idx = t * 4 + k;
        if (idx < NB) bstart[idx] = run;
        run += v[k];
    }
    if (t == 0) { bstart[NB] = N_EDGES; row_ptr[N_NODES] = N_EDGES; }
}

// scatter: per-chunk into tmp — contiguous runs per bucket (bases = cbaseT + bstart)
__global__ __launch_bounds__(256)
void scatter_coarse(const int* __restrict__ src, const int* __restrict__ dst,
                    const int* __restrict__ cbaseT, const int* __restrict__ bstart,
                    uint* __restrict__ tmp) {
    __shared__ int cur[NB];
    int c = blockIdx.x, t = threadIdx.x;
    for (int i = t; i < NB; i += 256) cur[i] = cbaseT[i * NCHUNK + c] + bstart[i];
    __syncthreads();
    const int4* s4p = (const int4*)src;
    const int4* d4p = (const int4*)dst;
#pragma unroll
    for (int k = 0; k < 2; ++k) {
        int i4 = c * (CHUNK / 4) + k * 256 + t;
        if (i4 < N_EDGES / 4) {
            int4 s = s4p[i4];
            int4 d = d4p[i4];
            int p;
            p = atomicAdd(&cur[d.x >> 7], 1); tmp[p] = (uint)s.x | (((uint)(d.x & 127)) << 17);
            p = atomicAdd(&cur[d.y >> 7], 1); tmp[p] = (uint)s.y | (((uint)(d.y & 127)) << 17);
            p = atomicAdd(&cur[d.z >> 7], 1); tmp[p] = (uint)s.z | (((uint)(d.z & 127)) << 17);
            p = atomicAdd(&cur[d.w >> 7], 1); tmp[p] = (uint)s.w | (((uint)(d.w & 127)) << 17);
        }
    }
}

// csr_fine: one block per 128-node bucket — local hist+scan -> row_ptr/dinv,
// fine scatter, fused xb8 = fp8(dinv * x)
__global__ __launch_bounds__(256)
void csr_fine(const uint* __restrict__ tmp, const int* __restrict__ bstart,
              int* __restrict__ row_ptr, float* __restrict__ dinv,
              int* __restrict__ edge, const float* __restrict__ x,
              uchar* __restrict__ xb8) {
    __shared__ int   cnt[128];
    __shared__ float dvloc[128];
    __shared__ int   ps[128];
    int b = blockIdx.x, t = threadIdx.x;
    int node0 = b << 7;
    int ncnt = min(128, N_NODES - node0);
    int s = bstart[b], e = bstart[b + 1];
    if (t < 128) cnt[t] = 0;
    __syncthreads();
    for (int i = s + t; i < e; i += 256) atomicAdd(&cnt[tmp[i] >> 17], 1);
    __syncthreads();
    int c0 = (t < 128) ? cnt[t] : 0;
    if (t < 128) ps[t] = c0;
    __syncthreads();
    for (int off = 1; off < 128; off <<= 1) {
        int v = (t < 128 && t >= off) ? ps[t - off] : 0;
        __syncthreads();
        if (t < 128) ps[t] += v;
        __syncthreads();
    }
    if (t < 128) {
        int p0 = s + ps[t] - c0;
        float dv = rsqrtf((float)(c0 + 1));
        if (t < ncnt) { row_ptr[node0 + t] = p0; dinv[node0 + t] = dv; }
        dvloc[t] = dv;
        cnt[t] = p0;                         // counts -> absolute cursors
    }
    __syncthreads();
    for (int i = s + t; i < e; i += 256) {
        uint rec = tmp[i];
        int p = atomicAdd(&cnt[rec >> 17], 1);
        edge[p] = (int)(rec & 0x1FFFFu);
    }
    // fused: xb8 rows for this bucket = fp8(dinv * x)  (4 feats -> 1 uint per idx)
    for (int idx = t; idx < ncnt * 16; idx += 256) {
        int row = idx >> 4, q = idx & 15;
        float4 f = ((const float4*)(x + (size_t)(node0 + row) * 64))[q];
        float d = dvloc[row];
        int w = __builtin_amdgcn_cvt_pk_fp8_f32(f.x * d, f.y * d, 0, false);
        w     = __builtin_amdgcn_cvt_pk_fp8_f32(f.z * d, f.w * d, w, true);
        *(uint*)(xb8 + (size_t)(node0 + row) * 64 + q * 4) = (uint)w;
    }
}

// ---------------- fused GCN conv ----------------
// input rows are G = dinv*H (fp8); agg_v = dinv_v * (sum_{s in N(v)} G_s + G_v)
// O = relu(agg @ W + b) [+ relu(tembb @ Wt + bt)]; SCALEOUT: store dinv*O
// R15: TILE=8 for K=128 convs (12500 waves of work) with MW=6 (VGPR cap 85 — fits
// the ~75-reg gather set, NO SPILLS). R14's MW=6-on-conv1/MW=7-on-conv2,3 forced
// VGPR=40 -> scratch spills (WRITE 43.75MB = spill traffic) yet still won 4us from
// occupancy 24->40% — proving concurrency pays; this round takes it without spills.
// conv1 (K=64, TILE=16) at MW=4: cap 128 >= natural 72, unconstrained.
template <int K, int TILE, int MW, bool TEMB, bool OUT8, bool SCALEOUT, bool POOL>
__global__ __launch_bounds__(256, MW)
void fused_conv(const void* __restrict__ Hv, const int* __restrict__ rp,
                const int* __restrict__ edge, const float* __restrict__ dinv,
                const ushort* __restrict__ Wp, const float* __restrict__ bias,
                const ushort* __restrict__ tembb, const ushort* __restrict__ Wtp,
                const float* __restrict__ bias_t, void* __restrict__ Ov,
                const int* __restrict__ batchp, float* __restrict__ pooled, int ntiles) {
    constexpr int LPR  = K / 16;      // lanes per row (16 fp8 feats/lane)
    constexpr int G    = 64 / LPR;    // concurrent rows per wave (8 or 16)
    static_assert(G >= TILE, "one row per group");
    constexpr int U    = 8;           // edge-walk unroll depth
    constexpr int LROW = 136;         // LDS row stride in shorts (bf16 staging)
    constexpr int ECAP = (TILE == 16) ? 512 : 256;  // span cap: mean 16*TILE+TILE deg
    __shared__ __align__(16) ushort sA[4][16 * LROW];
    __shared__ uint sE[4][ECAP];      // per-wave edge-span stage
    const int wave = threadIdx.x >> 6;
    const int lane = threadIdx.x & 63;
    const int tile = blockIdx.x * 4 + wave;
    if (tile >= ntiles) return;       // per-wave LDS, no barriers: safe
    const int row0 = tile * TILE;
    const int g  = lane / LPR;
    const int fq = lane % LPR;
    ushort* myA = sA[wave];
    const uchar* H8 = (const uchar*)Hv;

    // lane-parallel preload of row_ptr[TILE+1] / dinv[TILE]; broadcast via shfl
    int   rpv = rp[row0 + ((lane <= TILE) ? lane : TILE)];
    float dvv = dinv[row0 + ((lane < TILE) ? lane : TILE - 1)];

    // ---- stage the tile's contiguous edge span into LDS (coalesced) ----
    const int s0   = __shfl(rpv, 0);
    const int eT   = __shfl(rpv, TILE);
    const int ecnt = eT - s0;
    uint* sEw = sE[wave];
    for (int i = lane; i < ecnt && i < ECAP; i += 64)
        sEw[i] = ((const uint*)edge)[s0 + i];

    // ---- phase 1: each group gathers its own row (16B/lane, no reduce) ----
    auto phase1 = [&](auto eload) {
        int r = (g < TILE) ? g : TILE - 1;    // G==TILE always here; defensive
        int v = row0 + r;
        int s = __shfl(rpv, r), e = __shfl(rpv, r + 1);
        f32x2 a[8];
        // self-loop init: a = G_v
        {
            uint4 xv = *(const uint4*)(H8 + (size_t)v * K + fq * 16);
            a[0] = __builtin_amdgcn_cvt_pk_f32_fp8((int)xv.x, false);
            a[1] = __builtin_amdgcn_cvt_pk_f32_fp8((int)xv.x, true);
            a[2] = __builtin_amdgcn_cvt_pk_f32_fp8((int)xv.y, false);
            a[3] = __builtin_amdgcn_cvt_pk_f32_fp8((int)xv.y, true);
            a[4] = __builtin_amdgcn_cvt_pk_f32_fp8((int)xv.z, false);
            a[5] = __builtin_amdgcn_cvt_pk_f32_fp8((int)xv.z, true);
            a[6] = __builtin_amdgcn_cvt_pk_f32_fp8((int)xv.w, false);
            a[7] = __builtin_amdgcn_cvt_pk_f32_fp8((int)xv.w, true);
        }
        int nfull = (e - s) / U;          // group-uniform
        int j = s;
        for (int i = 0; i < nfull; ++i, j += U) {   // full batches: no masks
            int sv[U];
#pragma unroll
            for (int u = 0; u < U; ++u) sv[u] = eload(j + u);
            uint4 hv[U];
#pragma unroll
            for (int u = 0; u < U; ++u)
                hv[u] = *(const uint4*)(H8 + (size_t)sv[u] * K + fq * 16);
#pragma unroll
            for (int u = 0; u < U; ++u) acc16_pk(hv[u], a);
        }
        if (j < e) {                       // one masked tail batch
            int sv[U];
#pragma unroll
            for (int u = 0; u < U; ++u) {
                int jv = j + u;
                int jj = (jv < e) ? jv : e - 1;   // j<e => e>s => e-1 valid
                sv[u] = eload(jj);
            }
            uint4 hv[U];
#pragma unroll
            for (int u = 0; u < U; ++u)
                hv[u] = *(const uint4*)(H8 + (size_t)sv[u] * K + fq * 16);
#pragma unroll
            for (int u = 0; u < U; ++u) {
                float w = (j + u < e) ? 1.0f : 0.0f;
                acc16_w(hv[u], w, a);
            }
        }
        float dv = __shfl(dvv, r);        // row-uniform scale
        uint4 o1, o2;
        o1.x = pk(a[0].x * dv, a[0].y * dv); o1.y = pk(a[1].x * dv, a[1].y * dv);
        o1.z = pk(a[2].x * dv, a[2].y * dv); o1.w = pk(a[3].x * dv, a[3].y * dv);
        o2.x = pk(a[4].x * dv, a[4].y * dv); o2.y = pk(a[5].x * dv, a[5].y * dv);
        o2.z = pk(a[6].x * dv, a[6].y * dv); o2.w = pk(a[7].x * dv, a[7].y * dv);
        *(uint4*)(myA + r * LROW + fq * 16)     = o1;
        *(uint4*)(myA + r * LROW + fq * 16 + 8) = o2;
    };
    if (ecnt <= ECAP) {
        phase1([&](int jj) { return (int)sEw[jj - s0]; });       // LDS path (normal)
    } else {
        phase1([&](int jj) { return (int)((const uint*)edge)[jj]; });  // fallback
    }

    // ---- phase 2: MFMA (A from LDS, B packed from global/L2) ----
    // rows TILE..15 of myA are stale; C row i depends only on A row i -> safe.
    const int m = lane & 15, q = lane >> 4;
    f32x4 acc[8];
#pragma unroll
    for (int cb = 0; cb < 8; ++cb) acc[cb] = {0.f, 0.f, 0.f, 0.f};
    constexpr int S = K / 32;
#pragma unroll
    for (int s = 0; s < S; ++s) {
        short8 av = *(const short8*)(myA + m * LROW + s * 32 + q * 8);
#pragma unroll
        for (int cb = 0; cb < 8; ++cb) {
            short8 b = *(const short8*)(Wp + (size_t)((s * 8 + cb) * 64 + lane) * 8);
            acc[cb] = __builtin_amdgcn_mfma_f32_16x16x32_bf16(av, b, acc[cb], 0, 0, 0);
        }
    }

    // ---- phase 2b (TEMB): second MFMA chain, A = prepacked bf16 temb rows ----
    f32x4 acc2[TEMB ? 8 : 1];
    if constexpr (TEMB) {
#pragma unroll
        for (int cb = 0; cb < 8; ++cb) acc2[cb] = {0.f, 0.f, 0.f, 0.f};
        const ushort* Arow = tembb + (size_t)(row0 + m) * 128 + q * 8;
#pragma unroll
        for (int s2 = 0; s2 < 4; ++s2) {
            short8 av = *(const short8*)(Arow + s2 * 32);
#pragma unroll
            for (int cb = 0; cb < 8; ++cb) {
                short8 b = *(const short8*)(Wtp + (size_t)((s2 * 8 + cb) * 64 + lane) * 8);
                acc2[cb] = __builtin_amdgcn_mfma_f32_16x16x32_bf16(av, b, acc2[cb], 0, 0, 0);
            }
        }
    }

    // ---- phase 3: epilogue into LDS staging, then store / pool (TILE rows) ----
    // C/D layout: col = lane&15, row = (lane>>4)*4 + r
    float dsc[4];
    if constexpr (SCALEOUT) {
#pragma unroll
        for (int r = 0; r < 4; ++r) {
            int rr = q * 4 + r;
            dsc[r] = __shfl(dvv, (rr < TILE) ? rr : TILE - 1);
        }
    }
    if constexpr (!OUT8) {
        ushort* Ob = (ushort*)Ov;
#pragma unroll
        for (int cb = 0; cb < 8; ++cb) {
            int colc = cb * 16 + m;
            float bv = bias[colc];
            float bt2 = TEMB ? bias_t[colc] : 0.f;
#pragma unroll
            for (int r = 0; r < 4; ++r) {
                int row = q * 4 + r;
                float v = fmaxf(acc[cb][r] + bv, 0.0f);
                if (TEMB) v += fmaxf(acc2[cb][r] + bt2, 0.0f);
                if (SCALEOUT) v *= dsc[r];
                myA[row * LROW + colc] = f2bf(v);
            }
        }
        if constexpr (!POOL) {
#pragma unroll
            for (int i = 0; i < TILE / 4; ++i) {
                int srow = i * 4 + (lane >> 4);
                int scol = (lane & 15) * 8;
                *(short8*)(Ob + (size_t)(row0 + srow) * 128 + scol) =
                    *(const short8*)(myA + srow * LROW + scol);
            }
        } else {
            // per-graph segment sums over TILE rows (batch sorted), 2 cols/lane
            int gidv = (lane < TILE) ? batchp[row0 + lane] : 0;
            int colb = lane * 2;
            float p0 = 0.f, p1 = 0.f;
#pragma unroll
            for (int r = 0; r < TILE; ++r) {
                uint u = *(const uint*)(myA + r * LROW + colb);
                p0 += bflo(u); p1 += bfhi(u);
                int curg  = __shfl(gidv, r);
                int nextg = (r < TILE - 1) ? __shfl(gidv, r + 1) : -1;
                if (nextg != curg) {
                    atomicAdd(&pooled[curg * 128 + colb],     p0);
                    atomicAdd(&pooled[curg * 128 + colb + 1], p1);
                    p0 = 0.f; p1 = 0.f;
                }
            }
        }
    } else {
        uchar* st8 = (uchar*)myA;           // byte staging, row stride 136 B
        uchar* Ob = (uchar*)Ov;
#pragma unroll
        for (int cb = 0; cb < 8; ++cb) {
            int colc = cb * 16 + m;
            float bv = bias[colc];
            float bt2 = TEMB ? bias_t[colc] : 0.f;
#pragma unroll
            for (int r = 0; r < 4; ++r) {
                int row = q * 4 + r;
                float v = fmaxf(acc[cb][r] + bv, 0.0f);
                if (TEMB) v += fmaxf(acc2[cb][r] + bt2, 0.0f);
                if (SCALEOUT) v *= dsc[r];
                int enc = __builtin_amdgcn_cvt_pk_fp8_f32(v, v, 0, false);
                st8[row * 136 + colc] = (uchar)(enc & 0xff);
            }
        }
        // TILE rows * 128 B; 64 lanes * 8 B = 512 B/iter -> TILE/4 iters
#pragma unroll
        for (int i = 0; i < TILE / 4; ++i) {
            int idx = i * 64 + lane;        // [0, TILE*16)
            int srow = idx >> 4;            // [0, TILE)
            int soff = (idx & 15) * 8;      // [0,128) step 8
            *(uint2*)(Ob + (size_t)(row0 + srow) * 128 + soff) =
                *(const uint2*)(st8 + srow * 136 + soff);
        }
    }
}

// ---------------- output head: out[g] = (pooled[g]/cnt) @ Wo + bo ----------------

__global__ __launch_bounds__(256)
void head_kernel(const float* __restrict__ pooled, const int* __restrict__ gstart,
                 const float* __restrict__ Wo, const float* __restrict__ bo,
                 float* __restrict__ out) {
    int g  = blockIdx.x * 16 + (threadIdx.x >> 4);
    int tg = threadIdx.x & 15;
    if (g >= N_GRAPHS) return;
    int c = gstart[g + 1] - gstart[g];
    float inv = 1.0f / (float)(c < 1 ? 1 : c);
    float acc = bo[tg];
    for (int k = 0; k < HID; ++k)
        acc += pooled[g * 128 + k] * inv * Wo[k * 16 + tg];
    out[g * 16 + tg] = acc;
}

// ---------------- launch ----------------

extern "C" void kernel_launch(void* const* d_in, const int* in_sizes, int n_in,
                              void* d_out, int out_size, void* d_ws, size_t ws_size,
                              hipStream_t stream) {
    const float* x       = (const float*)d_in[0];
    const int*   ei      = (const int*)d_in[1];
    const float* temb_in = (const float*)d_in[2];
    const int*   batch   = (const int*)d_in[3];
    const float* Wt      = (const float*)d_in[4];
    const float* bt      = (const float*)d_in[5];
    const float* W1      = (const float*)d_in[6];
    const float* b1      = (const float*)d_in[7];
    const float* Ws      = (const float*)d_in[8];
    const float* bs      = (const float*)d_in[9];
    const float* Wo      = (const float*)d_in[10];
    const float* bo      = (const float*)d_in[11];
    float* out = (float*)d_out;

    const int N = N_NODES, E = N_EDGES;
    const int* src = ei;
    const int* dst = ei + E;

    char* p = (char*)d_ws;
    auto carve = [&](size_t bytes) -> void* {
        void* r = (void*)p;
        p += (bytes + 255) & ~(size_t)255;
        return r;
    };
    int*    row_ptr    = (int*)carve((size_t)(N + 1) * 4);
    float*  dinv       = (float*)carve((size_t)N * 4);
    int*    gstart     = (int*)carve((size_t)(N_GRAPHS + 1) * 4);
    ushort* packed     = (ushort*)carve((size_t)57344 * 2);
    int*    chunk_hist = (int*)carve((size_t)NCHUNK * NB * 4);
    int*    cbaseT     = (int*)carve((size_t)NB * NCHUNK * 4);
    int*    btotal     = (int*)carve((size_t)NB * 4);
    int*    bstart     = (int*)carve((size_t)(NB + 1) * 4);
    uint*   tmp        = (uint*)carve((size_t)E * 4);
    int*    edge       = (int*)carve((size_t)E * 4);
    uchar*  xb8        = (uchar*)carve((size_t)(N + 16) * 64);
    ushort* tembb      = (ushort*)carve((size_t)N * 128 * 2);
    uchar*  H1f8       = (uchar*)carve((size_t)(N + 16) * 128);
    uchar*  H2f8       = (uchar*)carve((size_t)(N + 16) * 128);
    float*  pooled     = (float*)carve((size_t)N_GRAPHS * 128 * 4);

    const ushort* Wtp  = packed;
    const ushort* W1p  = packed + 16384;
    const ushort* Ws0p = packed + 24576;
    const ushort* Ws1p = packed + 40960;

    const int nt16  = N / 16;             // 6250  (conv1: 16-row tiles)
    const int gblk1 = (nt16 + 3) / 4;     // 1563
    const int nt8   = N / 8;              // 12500 (conv2/3: 8-row tiles)
    const int gblk2 = (nt8 + 3) / 4;      // 3125

    // prep: pack W | boundaries | cvt temb | coarse hist | zero pooled
    prep_kernel<<<4778, 256, 0, stream>>>(Wt, W1, Ws, packed, batch, gstart,
                                          temb_in, tembb, dst, chunk_hist, pooled);

    // CSR build v3 (parallel scans; 782 buckets x 782 chunks)
    scanA<<<NB, 256, 0, stream>>>(chunk_hist, cbaseT, btotal);
    scanB<<<1, 256, 0, stream>>>(btotal, bstart, row_ptr);
    scatter_coarse<<<NCHUNK, 256, 0, stream>>>(src, dst, cbaseT, bstart, tmp);
    csr_fine<<<NB, 256, 0, stream>>>(tmp, bstart, row_ptr, dinv, edge, x, xb8);

    // conv1 (+fused temb layer, MW=4: unconstrained VGPR, no spills)
    fused_conv<64, 16, 4, true, true, true, false><<<gblk1, 256, 0, stream>>>(
        xb8, row_ptr, edge, dinv, W1p, b1, tembb, Wtp, bt, H1f8,
        nullptr, nullptr, nt16);
    // conv2 (fp8 gather, fp8 out, 8-row tiles, MW=6: 85-VGPR cap, no spills)
    fused_conv<128, 8, 6, false, true, true, false><<<gblk2, 256, 0, stream>>>(
        H1f8, row_ptr, edge, dinv, Ws0p, bs, nullptr, nullptr, nullptr, H2f8,
        nullptr, nullptr, nt8);
    // conv3 (fp8 gather, fused pooling, 8-row tiles, MW=6)
    fused_conv<128, 8, 6, false, false, false, true><<<gblk2, 256, 0, stream>>>(
        H2f8, row_ptr, edge, dinv, Ws1p, bs + 128, nullptr, nullptr, nullptr, nullptr,
        batch, pooled, nt8);

    // head: out = (pooled/cnt) @ Wo + bo
    head_kernel<<<32, 256, 0, stream>>>(pooled, gstart, Wo, bo, out);
}